// Round 4
// baseline (418.079 us; speedup 1.0000x reference)
//
#include <hip/hip_runtime.h>
#include <hip/hip_bf16.h>
#include <math.h>

// B=32, S=1, DIM=2048, NH=32, NKV=8, HD=64, L=2048, START_POS=2047.
// Inputs float32. OUTPUT float32.
#define NQKV 3072
#define NS 16     // flash-decode splits over L
#define SPL 128   // positions per split (2048 / NS)
#define KT 128    // GEMM LDS k-tile

__device__ __forceinline__ int read_sp(const int* spp) {
  if (!spp) return 2047;
  int raw = spp[0];
  if (raw >= 0 && raw < 2048) return raw;
  union { int i; float f; } u; u.i = raw;
  if (u.f >= 0.f && u.f < 2048.f) return (int)u.f;
  return 2047;
}

// ---------------- K0: x (f32 [32][2048]) -> xt (f32 [2048][32]) transposed
//                 + block 0 computes the RoPE cos/sin table (f64)
__global__ __launch_bounds__(256) void k_prep(const float* __restrict__ x,
                                              float* __restrict__ xt,
                                              float* __restrict__ rope,
                                              const int* __restrict__ spp) {
  int idx = blockIdx.x * 256 + threadIdx.x;   // 65536 total
  int r = idx >> 11, k = idx & 2047;
  xt[k * 32 + r] = x[idx];
  if (blockIdx.x == 0 && threadIdx.x < 32) {
    int i = threadIdx.x;
    int sp = read_sp(spp);
    double freq = pow(10000.0, -(double)(2 * i) / 64.0);
    double ang = (double)sp * freq;
    double sd, cd; sincos(ang, &sd, &cd);
    rope[2 * i]     = (float)cd;
    rope[2 * i + 1] = (float)sd;
  }
}

// ---------------- K1: QKV partial GEMM. Contiguous weight-row streaming.
// grid (6 colb, js). colb 0-3: qw 512-col slabs; 4: kw; 5: vw.
// Thread owns 2 cols; x-slice staged in LDS (broadcast reads).
__global__ __launch_bounds__(256) void k_qkv3(const float* __restrict__ qw,
                                              const float* __restrict__ kw,
                                              const float* __restrict__ vw,
                                              const float* __restrict__ xt,
                                              float* __restrict__ part, int kc) {
  int colb = blockIdx.x, j = blockIdx.y, t = threadIdx.x;
  const float* w; int ldw, col, outcol;
  if (colb < 4)       { w = qw; ldw = 2048; col = colb * 512 + t * 2; outcol = col; }
  else if (colb == 4) { w = kw; ldw = 512;  col = t * 2; outcol = 2048 + col; }
  else                { w = vw; ldw = 512;  col = t * 2; outcol = 2560 + col; }
  __shared__ __align__(16) float xs[KT][32];
  int k0 = j * kc;
  float2 acc[32];
  #pragma unroll
  for (int r = 0; r < 32; r++) { acc[r].x = 0.f; acc[r].y = 0.f; }
  for (int kt = 0; kt < kc; kt += KT) {
    int ksz = (kc - kt < KT) ? (kc - kt) : KT;
    __syncthreads();
    for (int idx = t; idx < ksz * 32; idx += 256)
      ((float*)xs)[idx] = xt[(size_t)(k0 + kt) * 32 + idx];
    __syncthreads();
    const float* wp = w + (size_t)(k0 + kt) * ldw + col;
    #pragma unroll 2
    for (int kk = 0; kk < ksz; kk++) {
      float2 wv = *(const float2*)&wp[(size_t)kk * ldw];
      #pragma unroll
      for (int r4 = 0; r4 < 8; r4++) {
        float4 xr = *(const float4*)&xs[kk][r4 * 4];
        acc[r4*4+0].x = fmaf(xr.x, wv.x, acc[r4*4+0].x);
        acc[r4*4+0].y = fmaf(xr.x, wv.y, acc[r4*4+0].y);
        acc[r4*4+1].x = fmaf(xr.y, wv.x, acc[r4*4+1].x);
        acc[r4*4+1].y = fmaf(xr.y, wv.y, acc[r4*4+1].y);
        acc[r4*4+2].x = fmaf(xr.z, wv.x, acc[r4*4+2].x);
        acc[r4*4+2].y = fmaf(xr.z, wv.y, acc[r4*4+2].y);
        acc[r4*4+3].x = fmaf(xr.w, wv.x, acc[r4*4+3].x);
        acc[r4*4+3].y = fmaf(xr.w, wv.y, acc[r4*4+3].y);
      }
    }
  }
  float* po = part + (size_t)j * (32 * NQKV) + outcol;
  #pragma unroll
  for (int r = 0; r < 32; r++) *(float2*)&po[(size_t)r * NQKV] = acc[r];
}

// ---------------- K1b: reduce K-split partials: qred[32][3072]
__global__ __launch_bounds__(256) void k_qred(const float* __restrict__ part,
                                              float* __restrict__ qred, int js) {
  int col = blockIdx.x * 256 + threadIdx.x;   // grid.x = 12
  int b = blockIdx.y;
  float s = 0.f;
  for (int j = 0; j < js; j++) s += part[(size_t)j * (32 * NQKV) + (size_t)b * NQKV + col];
  qred[(size_t)b * NQKV + col] = s;
}

// ---------------- K2: attention split, contiguous KV streaming.
// grid (NS, 32 b), 512 threads (8 waves). Block covers ALL 8 kv heads for
// SPL consecutive positions -> each position row [8h][64d] = 2048B read
// fully contiguously. wave = (w2 = pos quad, half = head half);
// lane = (hh2 = head in half)*16 + d4.
__global__ __launch_bounds__(512) void k_attn3(const float* __restrict__ ck,
                                               const float* __restrict__ cv,
                                               const float* __restrict__ qred,
                                               const float* __restrict__ rope,
                                               float* __restrict__ osplit,
                                               float* __restrict__ msl,
                                               const int* __restrict__ spp) {
  int s = blockIdx.x, b = blockIdx.y, tid = threadIdx.x;
  int sp = read_sp(spp);

  __shared__ __align__(16) float qs[8][4][64];
  __shared__ __align__(16) float knew[8][64];
  __shared__ __align__(16) float vnew[8][64];
  __shared__ __align__(16) float sc[8][4][SPL + 4];
  __shared__ __align__(16) float opart[4][8][4][64];

  const float* qb = qred + (size_t)b * NQKV;

  // stage: q with RoPE (1/8 folded), new k with RoPE, new v
  {
    int pi = tid * 2;
    #pragma unroll
    for (int u = 0; u < 2; u++, pi++) {       // 1024 q pairs
      int hq = pi >> 5, i = pi & 31;
      float cs = rope[2 * i], sn = rope[2 * i + 1];
      float a = qb[hq * 64 + 2 * i], bb = qb[hq * 64 + 2 * i + 1];
      qs[hq >> 2][hq & 3][2 * i]     = (a * cs - bb * sn) * 0.125f;
      qs[hq >> 2][hq & 3][2 * i + 1] = (a * sn + bb * cs) * 0.125f;
    }
    if (tid < 256) {                           // 256 k pairs
      int h = tid >> 5, i = tid & 31;
      float cs = rope[2 * i], sn = rope[2 * i + 1];
      float a = qb[2048 + h * 64 + 2 * i], bb = qb[2048 + h * 64 + 2 * i + 1];
      knew[h][2 * i]     = a * cs - bb * sn;
      knew[h][2 * i + 1] = a * sn + bb * cs;
    }
    { int h = tid >> 6, d = tid & 63; vnew[h][d] = qb[2560 + h * 64 + d]; }
  }
  __syncthreads();

  int w = tid >> 6, lane = tid & 63;
  int w2 = w >> 1, half = w & 1;
  int hh2 = lane >> 4, d4 = lane & 15;
  int h = half * 4 + hh2;

  float4 qv0 = *(const float4*)&qs[h][0][d4 * 4];
  float4 qv1 = *(const float4*)&qs[h][1][d4 * 4];
  float4 qv2 = *(const float4*)&qs[h][2][d4 * 4];
  float4 qv3 = *(const float4*)&qs[h][3][d4 * 4];
  float4 kn4 = *(const float4*)&knew[h][d4 * 4];
  float4 vn4 = *(const float4*)&vnew[h][d4 * 4];

  // pass 1: scores. lane float offset within row = half*256 + lane*4.
  const float* kb = ck + (size_t)b * 2048 * 512 + half * 256 + lane * 4;
  int pbase = s * SPL + w2;
  #pragma unroll 4
  for (int i = 0; i < 32; i++) {
    int p = pbase + i * 4;
    float4 k4 = *(const float4*)(kb + (size_t)p * 512);
    if (p == sp) k4 = kn4;
    float s0 = qv0.x * k4.x + qv0.y * k4.y + qv0.z * k4.z + qv0.w * k4.w;
    float s1 = qv1.x * k4.x + qv1.y * k4.y + qv1.z * k4.z + qv1.w * k4.w;
    float s2 = qv2.x * k4.x + qv2.y * k4.y + qv2.z * k4.z + qv2.w * k4.w;
    float s3 = qv3.x * k4.x + qv3.y * k4.y + qv3.z * k4.z + qv3.w * k4.w;
    #pragma unroll
    for (int off = 1; off <= 8; off <<= 1) {   // reduce over d4 (16 lanes)
      s0 += __shfl_xor(s0, off);
      s1 += __shfl_xor(s1, off);
      s2 += __shfl_xor(s2, off);
      s3 += __shfl_xor(s3, off);
    }
    float sv = (d4 == 0) ? s0 : (d4 == 1) ? s1 : (d4 == 2) ? s2 : s3;
    if (d4 < 4) sc[h][d4][p - s * SPL] = sv;
  }
  __syncthreads();

  // softmax: wave w owns rows w*4 .. w*4+3 (row = hq), SPL vals each
  #pragma unroll
  for (int q = 0; q < 4; q++) {
    int row = w * 4 + q, rh = row >> 2, rr = row & 3;
    float2 v01 = *(const float2*)&sc[rh][rr][lane * 2];
    float m = fmaxf(v01.x, v01.y);
    #pragma unroll
    for (int off = 1; off <= 32; off <<= 1) m = fmaxf(m, __shfl_xor(m, off));
    float e0 = __expf(v01.x - m), e1 = __expf(v01.y - m);
    sc[rh][rr][lane * 2] = e0; sc[rh][rr][lane * 2 + 1] = e1;
    float l = e0 + e1;
    #pragma unroll
    for (int off = 1; off <= 32; off <<= 1) l += __shfl_xor(l, off);
    if (lane == 0) {
      size_t mi = (((size_t)b * NS + s) * 32 + row) * 2;
      msl[mi] = m; msl[mi + 1] = l;
    }
  }
  __syncthreads();

  // pass 2: unnormalized o partials, same contiguous mapping for V
  const float* vb = cv + (size_t)b * 2048 * 512 + half * 256 + lane * 4;
  float4 a0 = {0,0,0,0}, a1 = {0,0,0,0}, a2 = {0,0,0,0}, a3 = {0,0,0,0};
  #pragma unroll 4
  for (int i = 0; i < 32; i++) {
    int p = pbase + i * 4;
    float4 v4 = *(const float4*)(vb + (size_t)p * 512);
    if (p == sp) v4 = vn4;
    int pl = p - s * SPL;
    float e0 = sc[h][0][pl], e1 = sc[h][1][pl], e2 = sc[h][2][pl], e3 = sc[h][3][pl];
    a0.x = fmaf(e0, v4.x, a0.x); a0.y = fmaf(e0, v4.y, a0.y);
    a0.z = fmaf(e0, v4.z, a0.z); a0.w = fmaf(e0, v4.w, a0.w);
    a1.x = fmaf(e1, v4.x, a1.x); a1.y = fmaf(e1, v4.y, a1.y);
    a1.z = fmaf(e1, v4.z, a1.z); a1.w = fmaf(e1, v4.w, a1.w);
    a2.x = fmaf(e2, v4.x, a2.x); a2.y = fmaf(e2, v4.y, a2.y);
    a2.z = fmaf(e2, v4.z, a2.z); a2.w = fmaf(e2, v4.w, a2.w);
    a3.x = fmaf(e3, v4.x, a3.x); a3.y = fmaf(e3, v4.y, a3.y);
    a3.z = fmaf(e3, v4.z, a3.z); a3.w = fmaf(e3, v4.w, a3.w);
  }
  *(float4*)&opart[w2][h][0][d4 * 4] = a0;
  *(float4*)&opart[w2][h][1][d4 * 4] = a1;
  *(float4*)&opart[w2][h][2][d4 * 4] = a2;
  *(float4*)&opart[w2][h][3][d4 * 4] = a3;
  __syncthreads();

  // cross-w2 reduce + write osplit. Output space = 8 heads * 4 reps * 64 dims
  // = 2048 elements (NOT 8192 — that was the r3 OOB bug).
  for (int e = tid; e < 2048; e += 512) {
    int eh = e >> 8, er = (e >> 6) & 3, ed = e & 63;
    float o = opart[0][eh][er][ed] + opart[1][eh][er][ed] +
              opart[2][eh][er][ed] + opart[3][eh][er][ed];
    osplit[(((size_t)b * NS + s) * 32 + eh * 4 + er) * 64 + ed] = o;
  }
}

// ---------------- K2b: flash-decode combine. grid (32 b, 4 g), 256 threads.
__global__ __launch_bounds__(256) void k_combine3(const float* __restrict__ osplit,
                                                  const float* __restrict__ msl,
                                                  float* __restrict__ obt) {
  int b = blockIdx.x, g = blockIdx.y, t = threadIdx.x;
  int hq = g * 8 + (t >> 5);
  int d0 = (t & 31) * 2;
  float ms[NS], ls[NS];
  float m = -1e30f;
  #pragma unroll
  for (int s = 0; s < NS; s++) {
    size_t mi = (((size_t)b * NS + s) * 32 + hq) * 2;
    ms[s] = msl[mi]; ls[s] = msl[mi + 1];
    m = fmaxf(m, ms[s]);
  }
  float L = 0.f, o0 = 0.f, o1 = 0.f;
  #pragma unroll
  for (int s = 0; s < NS; s++) {
    float wgt = __expf(ms[s] - m);
    L = fmaf(wgt, ls[s], L);
    const float* op = osplit + (((size_t)b * NS + s) * 32 + hq) * 64 + d0;
    o0 = fmaf(wgt, op[0], o0);
    o1 = fmaf(wgt, op[1], o1);
  }
  float invL = 1.f / L;
  obt[(size_t)(hq * 64 + d0) * 32 + b]     = o0 * invL;
  obt[(size_t)(hq * 64 + d0 + 1) * 32 + b] = o1 * invL;
}

// ---------------- K3: O partial GEMM, contiguous ow rows. grid (4 colb, js).
__global__ __launch_bounds__(256) void k_oproj3(const float* __restrict__ ow,
                                                const float* __restrict__ obt,
                                                float* __restrict__ part, int kc) {
  int colb = blockIdx.x, j = blockIdx.y, t = threadIdx.x;
  int col = colb * 512 + t * 2;
  __shared__ __align__(16) float xs[KT][32];
  int k0 = j * kc;
  float2 acc[32];
  #pragma unroll
  for (int r = 0; r < 32; r++) { acc[r].x = 0.f; acc[r].y = 0.f; }
  for (int kt = 0; kt < kc; kt += KT) {
    int ksz = (kc - kt < KT) ? (kc - kt) : KT;
    __syncthreads();
    for (int idx = t; idx < ksz * 32; idx += 256)
      ((float*)xs)[idx] = obt[(size_t)(k0 + kt) * 32 + idx];
    __syncthreads();
    const float* wp = ow + (size_t)(k0 + kt) * 2048 + col;
    #pragma unroll 2
    for (int kk = 0; kk < ksz; kk++) {
      float2 wv = *(const float2*)&wp[(size_t)kk * 2048];
      #pragma unroll
      for (int r4 = 0; r4 < 8; r4++) {
        float4 xr = *(const float4*)&xs[kk][r4 * 4];
        acc[r4*4+0].x = fmaf(xr.x, wv.x, acc[r4*4+0].x);
        acc[r4*4+0].y = fmaf(xr.x, wv.y, acc[r4*4+0].y);
        acc[r4*4+1].x = fmaf(xr.y, wv.x, acc[r4*4+1].x);
        acc[r4*4+1].y = fmaf(xr.y, wv.y, acc[r4*4+1].y);
        acc[r4*4+2].x = fmaf(xr.z, wv.x, acc[r4*4+2].x);
        acc[r4*4+2].y = fmaf(xr.z, wv.y, acc[r4*4+2].y);
        acc[r4*4+3].x = fmaf(xr.w, wv.x, acc[r4*4+3].x);
        acc[r4*4+3].y = fmaf(xr.w, wv.y, acc[r4*4+3].y);
      }
    }
  }
  float* po = part + (size_t)j * 65536 + col;
  #pragma unroll
  for (int r = 0; r < 32; r++) *(float2*)&po[(size_t)r * 2048] = acc[r];
}

// ---------------- K4: reduce K-split partials -> f32 output
__global__ __launch_bounds__(256) void k_finish(const float* __restrict__ part,
                                                float* __restrict__ out, int js) {
  int idx = blockIdx.x * 256 + threadIdx.x;  // 65536 = 32*2048
  float s = 0.f;
  for (int j = 0; j < js; j++) s += part[(size_t)j * 65536 + idx];
  out[idx] = s;
}

extern "C" void kernel_launch(void* const* d_in, const int* in_sizes, int n_in,
                              void* d_out, int out_size, void* d_ws, size_t ws_size,
                              hipStream_t stream) {
  const float* x  = (const float*)d_in[0];
  const float* qw = (const float*)d_in[1];
  const float* kw = (const float*)d_in[2];
  const float* vw = (const float*)d_in[3];
  const float* ow = (const float*)d_in[4];
  const float* ck = (const float*)d_in[5];
  const float* cv = (const float*)d_in[6];
  const int*   sp = (n_in >= 8) ? (const int*)d_in[7] : nullptr;

  // Workspace (floats): xt 65536 | part js*98304 | obt 65536 | qred 98304 |
  //                     osplit 1048576 | msl 32768 | rope 64
  const size_t FIXED = 65536 + 65536 + 98304 + 1048576 + 32768 + 64;
  int js = 2;
  {
    const int cands[5] = {32, 16, 8, 4, 2};
    for (int i = 0; i < 5; i++) {
      if ((FIXED + (size_t)cands[i] * 98304) * 4 <= ws_size) { js = cands[i]; break; }
    }
  }
  int kc = 2048 / js;

  float* ws     = (float*)d_ws;
  float* xt     = ws;
  float* part   = xt + 65536;
  float* obt    = part + (size_t)js * 98304;
  float* qred   = obt + 65536;
  float* osplit = qred + 98304;
  float* msl    = osplit + 1048576;
  float* rope   = msl + 32768;

  k_prep    <<<256,             256, 0, stream>>>(x, xt, rope, sp);
  k_qkv3    <<<dim3(6, js),     256, 0, stream>>>(qw, kw, vw, xt, part, kc);
  k_qred    <<<dim3(12, 32),    256, 0, stream>>>(part, qred, js);
  k_attn3   <<<dim3(NS, 32),    512, 0, stream>>>(ck, cv, qred, rope, osplit, msl, sp);
  k_combine3<<<dim3(32, 4),     256, 0, stream>>>(osplit, msl, obt);
  k_oproj3  <<<dim3(4, js),     256, 0, stream>>>(ow, obt, part, kc);
  k_finish  <<<256,             256, 0, stream>>>(part, (float*)d_out, js);
}

// Round 5
// 397.459 us; speedup vs baseline: 1.0519x; 1.0519x over previous
//
#include <hip/hip_runtime.h>
#include <hip/hip_fp16.h>
#include <hip/hip_bf16.h>
#include <math.h>

// B=32, S=1, DIM=2048, NH=32, NKV=8, HD=64, L=2048, START_POS=2047.
// Inputs float32. OUTPUT float32.
#define NQKV 3072
#define NS   8      // L-splits (block level)
#define SPL  256    // positions per block split
#define PW   64     // positions per wave (SPL/4)
#define NS4  32     // wave-level splits per (b): NS * 4

__device__ __forceinline__ int read_sp(const int* spp) {
  if (!spp) return 2047;
  int raw = spp[0];
  if (raw >= 0 && raw < 2048) return raw;
  union { int i; float f; } u; u.i = raw;
  if (u.f >= 0.f && u.f < 2048.f) return (int)u.f;
  return 2047;
}

// ---------------- K0: transpose x -> xt[2048][32], zero qkvacc + out,
//                  block 0 computes RoPE cos/sin table (f64 angles)
__global__ __launch_bounds__(256) void k_prep5(const float* __restrict__ x,
                                               float* __restrict__ xt,
                                               float* __restrict__ qkvacc,
                                               float* __restrict__ out,
                                               float* __restrict__ rope,
                                               const int* __restrict__ spp) {
  int idx = blockIdx.x * 256 + threadIdx.x;   // 65536 total
  int r = idx >> 11, k = idx & 2047;
  xt[k * 32 + r] = x[idx];
  out[idx] = 0.f;                              // 65536 = 32*2048
  for (int z = idx; z < 32 * NQKV; z += 65536) qkvacc[z] = 0.f;
  if (blockIdx.x == 0 && threadIdx.x < 32) {
    int i = threadIdx.x;
    int sp = read_sp(spp);
    double freq = pow(10000.0, -(double)(2 * i) / 64.0);
    double ang = (double)sp * freq;
    double sd, cd; sincos(ang, &sd, &cd);
    rope[2 * i]     = (float)cd;
    rope[2 * i + 1] = (float)sd;
  }
}

// ---------------- K1: QKV GEMM, k-split partials merged via atomicAdd.
// grid (6 colb, 32 j), 256 threads, kc=64. colb 0-3: qw slabs; 4: kw; 5: vw.
__global__ __launch_bounds__(256) void k_qkv5(const float* __restrict__ qw,
                                              const float* __restrict__ kw,
                                              const float* __restrict__ vw,
                                              const float* __restrict__ xt,
                                              float* __restrict__ qkvacc) {
  int colb = blockIdx.x, j = blockIdx.y, t = threadIdx.x;
  const float* w; int ldw, col, outcol;
  if (colb < 4)       { w = qw; ldw = 2048; col = colb * 512 + t * 2; outcol = col; }
  else if (colb == 4) { w = kw; ldw = 512;  col = t * 2; outcol = 2048 + col; }
  else                { w = vw; ldw = 512;  col = t * 2; outcol = 2560 + col; }
  __shared__ __align__(16) float xs[64][32];
  int k0 = j * 64;
  for (int i2 = t; i2 < 64 * 32; i2 += 256)
    ((float*)xs)[i2] = xt[(size_t)k0 * 32 + i2];
  __syncthreads();
  float2 acc[32];
  #pragma unroll
  for (int r = 0; r < 32; r++) { acc[r].x = 0.f; acc[r].y = 0.f; }
  const float* wp = w + (size_t)k0 * ldw + col;
  #pragma unroll 4
  for (int kk = 0; kk < 64; kk++) {
    float2 wv = *(const float2*)&wp[(size_t)kk * ldw];
    #pragma unroll
    for (int r4 = 0; r4 < 8; r4++) {
      float4 xr = *(const float4*)&xs[kk][r4 * 4];
      acc[r4*4+0].x = fmaf(xr.x, wv.x, acc[r4*4+0].x);
      acc[r4*4+0].y = fmaf(xr.x, wv.y, acc[r4*4+0].y);
      acc[r4*4+1].x = fmaf(xr.y, wv.x, acc[r4*4+1].x);
      acc[r4*4+1].y = fmaf(xr.y, wv.y, acc[r4*4+1].y);
      acc[r4*4+2].x = fmaf(xr.z, wv.x, acc[r4*4+2].x);
      acc[r4*4+2].y = fmaf(xr.z, wv.y, acc[r4*4+2].y);
      acc[r4*4+3].x = fmaf(xr.w, wv.x, acc[r4*4+3].x);
      acc[r4*4+3].y = fmaf(xr.w, wv.y, acc[r4*4+3].y);
    }
  }
  #pragma unroll
  for (int r = 0; r < 32; r++) {
    atomicAdd(&qkvacc[(size_t)r * NQKV + outcol],     acc[r].x);
    atomicAdd(&qkvacc[(size_t)r * NQKV + outcol + 1], acc[r].y);
  }
}

// ---------------- K2: fused single-pass flash attention.
// grid (NS, 32 b), 512 threads (8 waves). Block covers all 8 kv heads for
// SPL consecutive positions; each wave (w2, half) streams K AND V rows for
// its PW contiguous positions with online softmax, producing one flash split
// (m, l, unnormalized o in f16). No inter-pass barriers, LDS = 12.5 KB.
__global__ __launch_bounds__(512, 4) void k_attn5(const float* __restrict__ ck,
                                                  const float* __restrict__ cv,
                                                  const float* __restrict__ qkvacc,
                                                  const float* __restrict__ rope,
                                                  __half* __restrict__ osplit,
                                                  float* __restrict__ msl,
                                                  const int* __restrict__ spp) {
  int s = blockIdx.x, b = blockIdx.y, tid = threadIdx.x;
  int sp = read_sp(spp);

  __shared__ __align__(16) float qs[8][4][64];
  __shared__ __align__(16) float knew[8][64];
  __shared__ __align__(16) float vnew[8][64];

  const float* qb = qkvacc + (size_t)b * NQKV;

  // stage q (RoPE, 1/8 folded), new k (RoPE), new v
  {
    int pi = tid * 2;
    #pragma unroll
    for (int u = 0; u < 2; u++, pi++) {       // 1024 q pairs
      int hq = pi >> 5, i = pi & 31;
      float cs = rope[2 * i], sn = rope[2 * i + 1];
      float a = qb[hq * 64 + 2 * i], bb = qb[hq * 64 + 2 * i + 1];
      qs[hq >> 2][hq & 3][2 * i]     = (a * cs - bb * sn) * 0.125f;
      qs[hq >> 2][hq & 3][2 * i + 1] = (a * sn + bb * cs) * 0.125f;
    }
    if (tid < 256) {                           // 256 k pairs
      int h = tid >> 5, i = tid & 31;
      float cs = rope[2 * i], sn = rope[2 * i + 1];
      float a = qb[2048 + h * 64 + 2 * i], bb = qb[2048 + h * 64 + 2 * i + 1];
      knew[h][2 * i]     = a * cs - bb * sn;
      knew[h][2 * i + 1] = a * sn + bb * cs;
    }
    { int h = tid >> 6, d = tid & 63; vnew[h][d] = qb[2560 + h * 64 + d]; }
  }
  __syncthreads();

  int w = tid >> 6, lane = tid & 63;
  int w2 = w >> 1, half = w & 1;
  int hh2 = lane >> 4, d4 = lane & 15;
  int h = half * 4 + hh2;

  float4 qv0 = *(const float4*)&qs[h][0][d4 * 4];
  float4 qv1 = *(const float4*)&qs[h][1][d4 * 4];
  float4 qv2 = *(const float4*)&qs[h][2][d4 * 4];
  float4 qv3 = *(const float4*)&qs[h][3][d4 * 4];
  float4 kn4 = *(const float4*)&knew[h][d4 * 4];
  float4 vn4 = *(const float4*)&vnew[h][d4 * 4];

  const float* kb = ck + (size_t)b * 2048 * 512 + half * 256 + lane * 4;
  const float* vb = cv + (size_t)b * 2048 * 512 + half * 256 + lane * 4;
  int p0 = s * SPL + w2 * PW;

  float m0 = -1e30f, m1 = -1e30f, m2 = -1e30f, m3 = -1e30f;
  float l0 = 0.f, l1 = 0.f, l2 = 0.f, l3 = 0.f;
  float4 o0 = {0,0,0,0}, o1 = {0,0,0,0}, o2 = {0,0,0,0}, o3 = {0,0,0,0};

  #pragma unroll 4
  for (int i = 0; i < PW; i++) {
    int p = p0 + i;
    float4 k4 = *(const float4*)(kb + (size_t)p * 512);
    float4 v4 = *(const float4*)(vb + (size_t)p * 512);
    if (p == sp) { k4 = kn4; v4 = vn4; }
    float s0 = qv0.x * k4.x + qv0.y * k4.y + qv0.z * k4.z + qv0.w * k4.w;
    float s1 = qv1.x * k4.x + qv1.y * k4.y + qv1.z * k4.z + qv1.w * k4.w;
    float s2 = qv2.x * k4.x + qv2.y * k4.y + qv2.z * k4.z + qv2.w * k4.w;
    float s3 = qv3.x * k4.x + qv3.y * k4.y + qv3.z * k4.z + qv3.w * k4.w;
    #pragma unroll
    for (int off = 1; off <= 8; off <<= 1) {   // reduce over d4 (16 lanes)
      s0 += __shfl_xor(s0, off);
      s1 += __shfl_xor(s1, off);
      s2 += __shfl_xor(s2, off);
      s3 += __shfl_xor(s3, off);
    }
    // online softmax update per rep head
    float mn0 = fmaxf(m0, s0), c0 = __expf(m0 - mn0), e0 = __expf(s0 - mn0);
    float mn1 = fmaxf(m1, s1), c1 = __expf(m1 - mn1), e1 = __expf(s1 - mn1);
    float mn2 = fmaxf(m2, s2), c2 = __expf(m2 - mn2), e2 = __expf(s2 - mn2);
    float mn3 = fmaxf(m3, s3), c3 = __expf(m3 - mn3), e3 = __expf(s3 - mn3);
    l0 = fmaf(l0, c0, e0); l1 = fmaf(l1, c1, e1);
    l2 = fmaf(l2, c2, e2); l3 = fmaf(l3, c3, e3);
    m0 = mn0; m1 = mn1; m2 = mn2; m3 = mn3;
    o0.x = fmaf(e0, v4.x, o0.x * c0); o0.y = fmaf(e0, v4.y, o0.y * c0);
    o0.z = fmaf(e0, v4.z, o0.z * c0); o0.w = fmaf(e0, v4.w, o0.w * c0);
    o1.x = fmaf(e1, v4.x, o1.x * c1); o1.y = fmaf(e1, v4.y, o1.y * c1);
    o1.z = fmaf(e1, v4.z, o1.z * c1); o1.w = fmaf(e1, v4.w, o1.w * c1);
    o2.x = fmaf(e2, v4.x, o2.x * c2); o2.y = fmaf(e2, v4.y, o2.y * c2);
    o2.z = fmaf(e2, v4.z, o2.z * c2); o2.w = fmaf(e2, v4.w, o2.w * c2);
    o3.x = fmaf(e3, v4.x, o3.x * c3); o3.y = fmaf(e3, v4.y, o3.y * c3);
    o3.z = fmaf(e3, v4.z, o3.z * c3); o3.w = fmaf(e3, v4.w, o3.w * c3);
  }

  // write this wave-split's (m, l) and unnormalized o (f16)
  int s4 = s * 4 + w2;                          // 0..31
  size_t rowbase = ((size_t)b * NS4 + s4) * 32; // rows = q-heads (h*4+r)
  if (d4 == 0) {
    size_t mi;
    mi = (rowbase + h * 4 + 0) * 2; msl[mi] = m0; msl[mi + 1] = l0;
    mi = (rowbase + h * 4 + 1) * 2; msl[mi] = m1; msl[mi + 1] = l1;
    mi = (rowbase + h * 4 + 2) * 2; msl[mi] = m2; msl[mi + 1] = l2;
    mi = (rowbase + h * 4 + 3) * 2; msl[mi] = m3; msl[mi + 1] = l3;
  }
  {
    __half* op;
    op = osplit + (rowbase + h * 4 + 0) * 64 + d4 * 4;
    op[0] = __float2half(o0.x); op[1] = __float2half(o0.y);
    op[2] = __float2half(o0.z); op[3] = __float2half(o0.w);
    op = osplit + (rowbase + h * 4 + 1) * 64 + d4 * 4;
    op[0] = __float2half(o1.x); op[1] = __float2half(o1.y);
    op[2] = __float2half(o1.z); op[3] = __float2half(o1.w);
    op = osplit + (rowbase + h * 4 + 2) * 64 + d4 * 4;
    op[0] = __float2half(o2.x); op[1] = __float2half(o2.y);
    op[2] = __float2half(o2.z); op[3] = __float2half(o2.w);
    op = osplit + (rowbase + h * 4 + 3) * 64 + d4 * 4;
    op[0] = __float2half(o3.x); op[1] = __float2half(o3.y);
    op[2] = __float2half(o3.z); op[3] = __float2half(o3.w);
  }
}

// ---------------- K2b: flash combine over NS4 wave-splits. grid (32 b, 4 g).
__global__ __launch_bounds__(256) void k_combine5(const __half* __restrict__ osplit,
                                                  const float* __restrict__ msl,
                                                  float* __restrict__ obt) {
  int b = blockIdx.x, g = blockIdx.y, t = threadIdx.x;
  int hq = g * 8 + (t >> 5);
  int d0 = (t & 31) * 2;
  float m = -1e30f;
  for (int s4 = 0; s4 < NS4; s4++)
    m = fmaxf(m, msl[(((size_t)b * NS4 + s4) * 32 + hq) * 2]);
  float L = 0.f, o0 = 0.f, o1 = 0.f;
  for (int s4 = 0; s4 < NS4; s4++) {
    size_t mi = (((size_t)b * NS4 + s4) * 32 + hq) * 2;
    float wgt = __expf(msl[mi] - m);
    L = fmaf(wgt, msl[mi + 1], L);
    const __half* op = osplit + (((size_t)b * NS4 + s4) * 32 + hq) * 64 + d0;
    o0 = fmaf(wgt, __half2float(op[0]), o0);
    o1 = fmaf(wgt, __half2float(op[1]), o1);
  }
  float invL = 1.f / L;
  obt[(size_t)(hq * 64 + d0) * 32 + b]     = o0 * invL;
  obt[(size_t)(hq * 64 + d0 + 1) * 32 + b] = o1 * invL;
}

// ---------------- K3: O GEMM, k-split partials merged via atomicAdd into out.
// grid (4 colb, 32 j), 256 threads, kc=64.
__global__ __launch_bounds__(256) void k_oproj5(const float* __restrict__ ow,
                                                const float* __restrict__ obt,
                                                float* __restrict__ out) {
  int colb = blockIdx.x, j = blockIdx.y, t = threadIdx.x;
  int col = colb * 512 + t * 2;
  __shared__ __align__(16) float xs[64][32];
  int k0 = j * 64;
  for (int i2 = t; i2 < 64 * 32; i2 += 256)
    ((float*)xs)[i2] = obt[(size_t)k0 * 32 + i2];
  __syncthreads();
  float2 acc[32];
  #pragma unroll
  for (int r = 0; r < 32; r++) { acc[r].x = 0.f; acc[r].y = 0.f; }
  const float* wp = ow + (size_t)k0 * 2048 + col;
  #pragma unroll 4
  for (int kk = 0; kk < 64; kk++) {
    float2 wv = *(const float2*)&wp[(size_t)kk * 2048];
    #pragma unroll
    for (int r4 = 0; r4 < 8; r4++) {
      float4 xr = *(const float4*)&xs[kk][r4 * 4];
      acc[r4*4+0].x = fmaf(xr.x, wv.x, acc[r4*4+0].x);
      acc[r4*4+0].y = fmaf(xr.x, wv.y, acc[r4*4+0].y);
      acc[r4*4+1].x = fmaf(xr.y, wv.x, acc[r4*4+1].x);
      acc[r4*4+1].y = fmaf(xr.y, wv.y, acc[r4*4+1].y);
      acc[r4*4+2].x = fmaf(xr.z, wv.x, acc[r4*4+2].x);
      acc[r4*4+2].y = fmaf(xr.z, wv.y, acc[r4*4+2].y);
      acc[r4*4+3].x = fmaf(xr.w, wv.x, acc[r4*4+3].x);
      acc[r4*4+3].y = fmaf(xr.w, wv.y, acc[r4*4+3].y);
    }
  }
  #pragma unroll
  for (int r = 0; r < 32; r++) {
    atomicAdd(&out[(size_t)r * 2048 + col],     acc[r].x);
    atomicAdd(&out[(size_t)r * 2048 + col + 1], acc[r].y);
  }
}

extern "C" void kernel_launch(void* const* d_in, const int* in_sizes, int n_in,
                              void* d_out, int out_size, void* d_ws, size_t ws_size,
                              hipStream_t stream) {
  const float* x  = (const float*)d_in[0];
  const float* qw = (const float*)d_in[1];
  const float* kw = (const float*)d_in[2];
  const float* vw = (const float*)d_in[3];
  const float* ow = (const float*)d_in[4];
  const float* ck = (const float*)d_in[5];
  const float* cv = (const float*)d_in[6];
  const int*   sp = (n_in >= 8) ? (const int*)d_in[7] : nullptr;

  // Fixed workspace layout (floats):
  // xt 65536 | qkvacc 98304 | obt 65536 | msl 65536 | rope 64 | osplit 2M halves
  float* ws     = (float*)d_ws;
  float* xt     = ws;                         // 65536
  float* qkvacc = xt + 65536;                 // 98304
  float* obt    = qkvacc + 98304;             // 65536
  float* msl    = obt + 65536;                // 32*NS4*32*2 = 65536
  float* rope   = msl + 65536;                // 64
  __half* osplit = (__half*)(rope + 64);      // 32*NS4*32*64 = 2097152 halves
  float* out    = (float*)d_out;

  k_prep5   <<<256,          256, 0, stream>>>(x, xt, qkvacc, out, rope, sp);
  k_qkv5    <<<dim3(6, 32),  256, 0, stream>>>(qw, kw, vw, xt, qkvacc);
  k_attn5   <<<dim3(NS, 32), 512, 0, stream>>>(ck, cv, qkvacc, rope, osplit, msl, sp);
  k_combine5<<<dim3(32, 4),  256, 0, stream>>>(osplit, msl, obt);
  k_oproj5  <<<dim3(4, 32),  256, 0, stream>>>(ow, obt, out);
}